// Round 4
// baseline (285.902 us; speedup 1.0000x reference)
//
#include <hip/hip_runtime.h>
#include <hip/hip_bf16.h>

#define C_IN   256
#define C_OUT  512
#define NFILT  4

#define BM  32
#define SAS 264   // LDS A-row stride in bf16 elems (256+8)

typedef __attribute__((ext_vector_type(8))) short bf16x8;
typedef __attribute__((ext_vector_type(4))) float floatx4;
typedef __attribute__((ext_vector_type(4))) float f4v;

union Pack8 { uint4 u; __hip_bfloat16 h[8]; };

__global__ void zero_cnt_kernel(int* __restrict__ cnt) {
    if (threadIdx.x < NFILT) cnt[threadIdx.x] = 0;
}

__global__ void bucketize_kernel(const float* __restrict__ xyz,
                                 int* __restrict__ idxbuf,
                                 int* __restrict__ cnt, int P) {
    int pid = blockIdx.x * blockDim.x + threadIdx.x;
    if (pid >= P) return;
    float x = xyz[pid * 3 + 0];
    float y = xyz[pid * 3 + 1];
    float z = xyz[pid * 3 + 2];
    float r2 = __fadd_rn(__fadd_rn(__fmul_rn(x, x), __fmul_rn(y, y)), __fmul_rn(z, z));
    float r = sqrtf(r2);
    int filt;
    if (r < 1.0f)        filt = 0;
    else if (r < 1.5f)   filt = 1;
    else if (r < 2.0f)   filt = 2;
    else if (r < 100.0f) filt = 3;
    else                 filt = 0;   // argmax over all-false returns 0

    int lane = threadIdx.x & 63;
    for (int f = 0; f < NFILT; ++f) {
        unsigned long long mask = __ballot(filt == f);
        if (mask == 0ull) continue;
        int leader = __ffsll((unsigned long long)mask) - 1;
        int base = 0;
        if (lane == leader) base = atomicAdd(&cnt[f], __popcll(mask));
        base = __shfl(base, leader);
        if (filt == f) {
            int off = __popcll(mask & ((1ull << lane) - 1ull));
            idxbuf[f * P + base + off] = pid;
        }
    }
}

// w[f][o][c] fp32 -> fragment-linear bf16:
// wbt[(f*32 + ot*8 + kk)*4096 + j*512 + (quad*16+lcol)*8 + e]
// where o = ot*128 + j*16 + lcol, c = kk*32 + quad*8 + e.
// A wave's b-frag load (fixed j,kk) is then 64 lanes x 16B contiguous.
__global__ void convert_w_kernel(const float* __restrict__ w,
                                 ushort* __restrict__ wbt) {
    int t = blockIdx.x * blockDim.x + threadIdx.x;   // 64K threads, 8 elems each
    int c8 = t & 31;
    int fo = t >> 5;
    int f  = fo >> 9;
    int o  = fo & 511;
    int ot = o >> 7, j = (o >> 4) & 7, lc = o & 15;
    int kk = c8 >> 2, quad = c8 & 3;
    const float* src = w + (size_t)fo * C_IN + c8 * 8;
    f4v v0 = *(const f4v*)(src + 0);
    f4v v1 = *(const f4v*)(src + 4);
    Pack8 p;
    p.h[0] = __float2bfloat16(v0.x); p.h[1] = __float2bfloat16(v0.y);
    p.h[2] = __float2bfloat16(v0.z); p.h[3] = __float2bfloat16(v0.w);
    p.h[4] = __float2bfloat16(v1.x); p.h[5] = __float2bfloat16(v1.y);
    p.h[6] = __float2bfloat16(v1.z); p.h[7] = __float2bfloat16(v1.w);
    size_t dst = (size_t)(f * 32 + ot * 8 + kk) * 4096 + j * 512 + (quad * 16 + lc) * 8;
    *(uint4*)(wbt + dst) = p.u;
}

__global__ __launch_bounds__(256, 3) void gemm_kernel(
    const float* __restrict__ feat, const ushort* __restrict__ wbt,
    const float* __restrict__ bias, const int* __restrict__ idxbuf,
    const int* __restrict__ cnt, float* __restrict__ out, int P)
{
    __shared__ ushort sA[BM * SAS];    // ~16.9 KB
    __shared__ float  sBias[C_OUT];
    __shared__ int    sIdx[BM];

    // map linear block id -> (filter f, local row-tile lt)
    int t = blockIdx.x;
    int f = -1, lt = 0, cn = 0;
    for (int ff = 0; ff < NFILT; ++ff) {
        int c = cnt[ff];
        int nt = (c + BM - 1) / BM;
        if (t < nt) { f = ff; lt = t; cn = c; break; }
        t -= nt;
    }
    if (f < 0) return;

    int tid = threadIdx.x;
    int rowBase = lt * BM;
    if (tid < BM) {
        int r = rowBase + tid;
        sIdx[tid] = (r < cn) ? idxbuf[f * P + r] : -1;
    }
    sBias[tid]       = bias[f * C_OUT + tid];
    sBias[tid + 256] = bias[f * C_OUT + tid + 256];
    __syncthreads();

    // ---- stage A: 32 rows x 256 k, fp32 gather -> bf16 LDS ----
    {
        int row = tid >> 3, c0 = (tid & 7) * 32;
        int myIdx = sIdx[row];
        const float* ap = feat + (size_t)(myIdx < 0 ? 0 : myIdx) * C_IN + c0;
        ushort* dA = &sA[row * SAS + c0];
#pragma unroll
        for (int it = 0; it < 2; ++it) {
            f4v a0 = __builtin_nontemporal_load((const f4v*)(ap + it * 16 + 0));
            f4v a1 = __builtin_nontemporal_load((const f4v*)(ap + it * 16 + 4));
            f4v a2 = __builtin_nontemporal_load((const f4v*)(ap + it * 16 + 8));
            f4v a3 = __builtin_nontemporal_load((const f4v*)(ap + it * 16 + 12));
            Pack8 p0, p1;
            p0.h[0] = __float2bfloat16(a0.x); p0.h[1] = __float2bfloat16(a0.y);
            p0.h[2] = __float2bfloat16(a0.z); p0.h[3] = __float2bfloat16(a0.w);
            p0.h[4] = __float2bfloat16(a1.x); p0.h[5] = __float2bfloat16(a1.y);
            p0.h[6] = __float2bfloat16(a1.z); p0.h[7] = __float2bfloat16(a1.w);
            p1.h[0] = __float2bfloat16(a2.x); p1.h[1] = __float2bfloat16(a2.y);
            p1.h[2] = __float2bfloat16(a2.z); p1.h[3] = __float2bfloat16(a2.w);
            p1.h[4] = __float2bfloat16(a3.x); p1.h[5] = __float2bfloat16(a3.y);
            p1.h[6] = __float2bfloat16(a3.z); p1.h[7] = __float2bfloat16(a3.w);
            *(uint4*)(dA + it * 16 + 0) = p0.u;
            *(uint4*)(dA + it * 16 + 8) = p1.u;
        }
    }
    __syncthreads();

    // ---- compute: each wave owns one 128-col o-tile, all 32 rows ----
    int wOT  = tid >> 6;           // o-tile index 0..3
    int lane = tid & 63;
    int lcol = lane & 15, quad = lane >> 4;

    const ushort* bPtr = wbt + (size_t)(f * 32 + wOT * 8) * 4096
                             + (size_t)(quad * 16 + lcol) * 8;
    int aOff0 = lcol * SAS + quad * 8;
    int aOff1 = (16 + lcol) * SAS + quad * 8;

    floatx4 acc[2][8];
#pragma unroll
    for (int i = 0; i < 2; ++i)
#pragma unroll
        for (int j = 0; j < 8; ++j)
            acc[i][j] = (floatx4){0.f, 0.f, 0.f, 0.f};

    // barrier-free K-loop: compiler is free to pipeline B loads across kk
#pragma unroll
    for (int kk = 0; kk < 8; ++kk) {
        bf16x8 af0 = *(const bf16x8*)&sA[aOff0 + kk * 32];
        bf16x8 af1 = *(const bf16x8*)&sA[aOff1 + kk * 32];
        bf16x8 bfr[8];
        const ushort* bk = bPtr + (size_t)kk * 4096;
#pragma unroll
        for (int j = 0; j < 8; ++j)
            bfr[j] = *(const bf16x8*)(bk + j * 512);
#pragma unroll
        for (int j = 0; j < 8; ++j) {
            acc[0][j] = __builtin_amdgcn_mfma_f32_16x16x32_bf16(af0, bfr[j], acc[0][j], 0, 0, 0);
            acc[1][j] = __builtin_amdgcn_mfma_f32_16x16x32_bf16(af1, bfr[j], acc[1][j], 0, 0, 0);
        }
    }

    // ---- epilogue: scatter rows, add bias, plain stores (L2 write-combine) ----
    int pid_[2][4];
#pragma unroll
    for (int i = 0; i < 2; ++i)
#pragma unroll
        for (int r = 0; r < 4; ++r)
            pid_[i][r] = sIdx[i * 16 + quad * 4 + r];

#pragma unroll
    for (int j = 0; j < 8; ++j) {
        int o = wOT * 128 + j * 16 + lcol;
        float bv = sBias[o];
#pragma unroll
        for (int i = 0; i < 2; ++i)
#pragma unroll
            for (int r = 0; r < 4; ++r)
                if (pid_[i][r] >= 0)
                    out[(size_t)pid_[i][r] * C_OUT + o] = acc[i][j][r] + bv;
    }
}

extern "C" void kernel_launch(void* const* d_in, const int* in_sizes, int n_in,
                              void* d_out, int out_size, void* d_ws, size_t ws_size,
                              hipStream_t stream) {
    const float* feat = (const float*)d_in[0];
    const float* xyz  = (const float*)d_in[1];
    const float* w    = (const float*)d_in[2];
    const float* bias = (const float*)d_in[3];
    float* out = (float*)d_out;
    int P = in_sizes[0] / C_IN;

    char* ws = (char*)d_ws;
    int* idxbuf = (int*)ws;                                    // 4*P ints
    int* cntp   = (int*)(ws + (size_t)4 * P * 4);              // 4 ints (+pad)
    ushort* wbt = (ushort*)(ws + (size_t)4 * P * 4 + 16);      // NFILT*C_OUT*C_IN bf16

    zero_cnt_kernel<<<1, 64, 0, stream>>>(cntp);
    bucketize_kernel<<<(P + 255) / 256, 256, 0, stream>>>(xyz, idxbuf, cntp, P);
    convert_w_kernel<<<(NFILT * C_OUT * C_IN / 8 + 255) / 256, 256, 0, stream>>>(w, wbt);

    dim3 grid(P / BM + NFILT);
    gemm_kernel<<<grid, 256, 0, stream>>>(feat, wbt, bias, idxbuf, cntp, out, P);
}